// Round 1
// baseline (1734.506 us; speedup 1.0000x reference)
//
#include <hip/hip_runtime.h>
#include <math.h>

#define DIM 768
#define NTOK 1024
#define NBATCH 16
#define BN (NBATCH * NTOK)

__device__ __forceinline__ float geluf(float z) {
    // exact gelu: 0.5*z*(1+erf(z/sqrt(2)))
    return 0.5f * z * (1.0f + erff(z * 0.70710678118654752440f));
}

__device__ __forceinline__ float block_sum(float v, float* sbuf) {
    #pragma unroll
    for (int o = 32; o > 0; o >>= 1) v += __shfl_down(v, o, 64);
    const int lane = threadIdx.x & 63, w = threadIdx.x >> 6;
    if (lane == 0) sbuf[w] = v;
    __syncthreads();
    const float r = sbuf[0] + sbuf[1] + sbuf[2] + sbuf[3];
    __syncthreads();   // protect sbuf before next reuse
    return r;
}

// avg_x[b,d] = mean over n of x[b,n,d]
__global__ __launch_bounds__(256) void avg_kernel(const float* __restrict__ x,
                                                  float* __restrict__ avgx) {
    const int d = blockIdx.x * 256 + threadIdx.x;
    const int b = blockIdx.y;
    const float* xp = x + (size_t)b * NTOK * DIM + d;
    float s = 0.0f;
    for (int n = 0; n < NTOK; ++n) s += xp[(size_t)n * DIM];
    avgx[b * DIM + d] = s * (1.0f / NTOK);
}

// per-token LN -> sigmoid -> A = avg_x * sig ; sq[r] = sum(A^2)
__global__ __launch_bounds__(256) void ln_sig_kernel(
    const float* __restrict__ x, const float* __restrict__ gamma,
    const float* __restrict__ beta, const float* __restrict__ avgx,
    float* __restrict__ A, float* __restrict__ sq)
{
    __shared__ float sbuf[4];
    const int row = blockIdx.x;          // 0..BN-1
    const int b = row >> 10;             // NTOK = 1024
    const int tid = threadIdx.x;
    const float* xr = x + (size_t)row * DIM;
    float v[3];
    #pragma unroll
    for (int i = 0; i < 3; ++i) v[i] = xr[tid + 256 * i];
    const float mu = block_sum(v[0] + v[1] + v[2], sbuf) * (1.0f / DIM);
    float ss = 0.0f;
    #pragma unroll
    for (int i = 0; i < 3; ++i) { const float d = v[i] - mu; ss += d * d; }
    const float var = block_sum(ss, sbuf) * (1.0f / DIM);
    const float rstd = rsqrtf(var + 1e-5f);
    const float* ag = avgx + b * DIM;
    float qs = 0.0f;
    #pragma unroll
    for (int i = 0; i < 3; ++i) {
        const int d = tid + 256 * i;
        const float ln = (v[i] - mu) * rstd * gamma[d] + beta[d];
        const float sg = 1.0f / (1.0f + expf(-ln));
        const float a = ag[d] * sg;
        A[(size_t)row * DIM + d] = a;
        qs += a * a;
    }
    const float tot = block_sum(qs, sbuf);
    if (tid == 0) sq[row] = tot;
}

// per batch: m[i] = max_j sqrt(max(sq_i + sq_j - 2*A_i.A_j, 1e-12))
// upper-triangular 64x64 tiles; atomicMax on positive-float bit pattern.
__global__ __launch_bounds__(256) void dist_max_kernel(
    const float* __restrict__ A, const float* __restrict__ sq,
    float* __restrict__ m)
{
    __shared__ __align__(16) float As[16][68];
    __shared__ __align__(16) float Bs[16][68];
    __shared__ float red[2][64][16];
    const int b = blockIdx.y;
    int rem = blockIdx.x, I = 0;
    while (rem >= 16 - I) { rem -= 16 - I; ++I; }
    const int J = I + rem;                       // J >= I
    const int base = b * NTOK;
    const int tid = threadIdx.x;
    const int tx = tid & 15, ty = tid >> 4;
    const int ai = tid >> 2, ak = (tid & 3) * 4;
    float acc[4][4] = {};
    const float* Ai = A + (size_t)(base + I * 64) * DIM;
    const float* Aj = A + (size_t)(base + J * 64) * DIM;
    for (int k0 = 0; k0 < DIM; k0 += 16) {
        const float4 av = *(const float4*)&Ai[(size_t)ai * DIM + k0 + ak];
        const float4 bv = *(const float4*)&Aj[(size_t)ai * DIM + k0 + ak];
        As[ak + 0][ai] = av.x; As[ak + 1][ai] = av.y;
        As[ak + 2][ai] = av.z; As[ak + 3][ai] = av.w;
        Bs[ak + 0][ai] = bv.x; Bs[ak + 1][ai] = bv.y;
        Bs[ak + 2][ai] = bv.z; Bs[ak + 3][ai] = bv.w;
        __syncthreads();
        #pragma unroll
        for (int kk = 0; kk < 16; ++kk) {
            const float4 a4 = *(const float4*)&As[kk][ty * 4];
            const float4 b4 = *(const float4*)&Bs[kk][tx * 4];
            const float aa[4] = {a4.x, a4.y, a4.z, a4.w};
            const float bb[4] = {b4.x, b4.y, b4.z, b4.w};
            #pragma unroll
            for (int r = 0; r < 4; ++r)
                #pragma unroll
                for (int c = 0; c < 4; ++c)
                    acc[r][c] = fmaf(aa[r], bb[c], acc[r][c]);
        }
        __syncthreads();
    }
    float sqi[4], sqj[4];
    #pragma unroll
    for (int r = 0; r < 4; ++r) sqi[r] = sq[base + I * 64 + ty * 4 + r];
    #pragma unroll
    for (int c = 0; c < 4; ++c) sqj[c] = sq[base + J * 64 + tx * 4 + c];
    float rowm[4] = {0, 0, 0, 0}, colm[4] = {0, 0, 0, 0};
    #pragma unroll
    for (int r = 0; r < 4; ++r)
        #pragma unroll
        for (int c = 0; c < 4; ++c) {
            const float d2 = sqi[r] + sqj[c] - 2.0f * acc[r][c];
            const float d = sqrtf(fmaxf(d2, 1e-12f));
            rowm[r] = fmaxf(rowm[r], d);
            colm[c] = fmaxf(colm[c], d);
        }
    #pragma unroll
    for (int r = 0; r < 4; ++r) red[0][ty * 4 + r][tx] = rowm[r];
    #pragma unroll
    for (int c = 0; c < 4; ++c) red[1][tx * 4 + c][ty] = colm[c];
    __syncthreads();
    if (tid < 64) {
        float v = red[0][tid][0];
        #pragma unroll
        for (int k = 1; k < 16; ++k) v = fmaxf(v, red[0][tid][k]);
        atomicMax((unsigned int*)&m[base + I * 64 + tid], __float_as_uint(v));
    } else if (tid < 128) {
        const int j = tid - 64;
        float v = red[1][j][0];
        #pragma unroll
        for (int k = 1; k < 16; ++k) v = fmaxf(v, red[1][j][k]);
        atomicMax((unsigned int*)&m[base + J * 64 + j], __float_as_uint(v));
    }
}

// out = gelu(Aact(@cat) @ Wm + bias) [* epilogue factors]
// CAT: cols [0,768) from Aact (stride 768), cols [768,1536) = x + m (per row)
// EPI 0: gelu ; EPI 1: gelu * e1 * x ; EPI 2: gelu * x
template<bool CAT, int EPI>
__global__ __launch_bounds__(256) void gemm_fused(
    const float* __restrict__ Aact, const float* __restrict__ Wm,
    const float* __restrict__ bias, const float* __restrict__ xin,
    const float* __restrict__ mvec, const float* __restrict__ e1,
    float* __restrict__ outp, int K)
{
    __shared__ __align__(16) float As[16][68];
    __shared__ __align__(16) float Bs[16][68];
    const int tid = threadIdx.x;
    const int tx = tid & 15, ty = tid >> 4;
    const int R0 = blockIdx.y * 64, J0 = blockIdx.x * 64;
    const int ai = tid >> 2, ak = (tid & 3) * 4;
    const int bk = tid >> 4, bj = (tid & 15) * 4;
    const int ra = R0 + ai;
    float mv = 0.0f;
    if (CAT) mv = mvec[ra];
    float acc[4][4] = {};
    for (int k0 = 0; k0 < K; k0 += 16) {
        float4 av;
        if (CAT && k0 >= DIM) {
            const float4 xv = *(const float4*)&xin[(size_t)ra * DIM + (k0 - DIM) + ak];
            av = make_float4(xv.x + mv, xv.y + mv, xv.z + mv, xv.w + mv);
        } else {
            av = *(const float4*)&Aact[(size_t)ra * DIM + k0 + ak];
        }
        As[ak + 0][ai] = av.x; As[ak + 1][ai] = av.y;
        As[ak + 2][ai] = av.z; As[ak + 3][ai] = av.w;
        *(float4*)&Bs[bk][bj] = *(const float4*)&Wm[(size_t)(k0 + bk) * DIM + J0 + bj];
        __syncthreads();
        #pragma unroll
        for (int kk = 0; kk < 16; ++kk) {
            const float4 a4 = *(const float4*)&As[kk][ty * 4];
            const float4 b4 = *(const float4*)&Bs[kk][tx * 4];
            const float aa[4] = {a4.x, a4.y, a4.z, a4.w};
            const float bb[4] = {b4.x, b4.y, b4.z, b4.w};
            #pragma unroll
            for (int r = 0; r < 4; ++r)
                #pragma unroll
                for (int c = 0; c < 4; ++c)
                    acc[r][c] = fmaf(aa[r], bb[c], acc[r][c]);
        }
        __syncthreads();
    }
    const float4 bv4 = *(const float4*)&bias[J0 + tx * 4];
    const float bbias[4] = {bv4.x, bv4.y, bv4.z, bv4.w};
    #pragma unroll
    for (int r = 0; r < 4; ++r) {
        const int row = R0 + ty * 4 + r;
        const size_t off = (size_t)row * DIM + J0 + tx * 4;
        float o[4];
        #pragma unroll
        for (int c = 0; c < 4; ++c) o[c] = geluf(acc[r][c] + bbias[c]);
        if (EPI == 1) {
            const float4 xv = *(const float4*)&xin[off];
            const float4 ev = *(const float4*)&e1[off];
            o[0] *= xv.x * ev.x; o[1] *= xv.y * ev.y;
            o[2] *= xv.z * ev.z; o[3] *= xv.w * ev.w;
        } else if (EPI == 2) {
            const float4 xv = *(const float4*)&xin[off];
            o[0] *= xv.x; o[1] *= xv.y; o[2] *= xv.z; o[3] *= xv.w;
        }
        *(float4*)&outp[off] = make_float4(o[0], o[1], o[2], o[3]);
    }
}

extern "C" void kernel_launch(void* const* d_in, const int* in_sizes, int n_in,
                              void* d_out, int out_size, void* d_ws, size_t ws_size,
                              hipStream_t stream)
{
    const float* x     = (const float*)d_in[0];
    const float* gamma = (const float*)d_in[1];
    const float* beta  = (const float*)d_in[2];
    const float* w1    = (const float*)d_in[3];
    const float* b1    = (const float*)d_in[4];
    const float* w2    = (const float*)d_in[5];
    const float* b2    = (const float*)d_in[6];
    const float* w3    = (const float*)d_in[7];
    const float* b3    = (const float*)d_in[8];
    const float* w4    = (const float*)d_in[9];
    const float* b4    = (const float*)d_in[10];
    float* out = (float*)d_out;
    float* ws  = (float*)d_ws;

    // ws layout (floats): avgx[12288] | sq[16384] | m[16384] | big[BN*DIM]
    float* avgx = ws;
    float* sq   = ws + 12288;
    float* mbuf = ws + 12288 + 16384;
    float* big  = ws + 12288 + 16384 + 16384;   // 50.3 MB ping buffer

    // Buffer plan: A -> d_out ; m1 -> big ; h3in -> d_out ; h4in -> big ; out -> d_out
    hipMemsetAsync(mbuf, 0, BN * sizeof(float), stream);
    avg_kernel<<<dim3(DIM / 256, NBATCH), 256, 0, stream>>>(x, avgx);
    ln_sig_kernel<<<dim3(BN), 256, 0, stream>>>(x, gamma, beta, avgx, out, sq);
    dist_max_kernel<<<dim3(136, NBATCH), 256, 0, stream>>>(out, sq, mbuf);
    // L1: m1 = gelu(cat @ w1 + b1), cat = [A(d_out), x+m]
    gemm_fused<true, 0><<<dim3(DIM / 64, BN / 64), 256, 0, stream>>>(
        out, w1, b1, x, mbuf, nullptr, big, 2 * DIM);
    // L2: h3in = m1 * x * gelu(m1 @ w2 + b2)   (= m1 * Wdyn)
    gemm_fused<false, 1><<<dim3(DIM / 64, BN / 64), 256, 0, stream>>>(
        big, w2, b2, x, nullptr, big, out, DIM);
    // L3: h4in = x * gelu(h3in @ w3 + b3)
    gemm_fused<false, 2><<<dim3(DIM / 64, BN / 64), 256, 0, stream>>>(
        out, w3, b3, x, nullptr, nullptr, big, DIM);
    // L4: out = gelu(h4in @ w4 + b4)
    gemm_fused<false, 0><<<dim3(DIM / 64, BN / 64), 256, 0, stream>>>(
        big, w4, b4, x, nullptr, nullptr, out, DIM);
}

// Round 2
// 504.605 us; speedup vs baseline: 3.4374x; 3.4374x over previous
//
#include <hip/hip_runtime.h>
#include <hip/hip_fp16.h>
#include <math.h>

#define DIM 768
#define NTOK 1024
#define NBATCH 16
#define BNR (NBATCH * NTOK)   // 16384 rows

typedef _Float16 f16x8 __attribute__((ext_vector_type(8)));
typedef float f32x4 __attribute__((ext_vector_type(4)));

// async global->LDS, 16B per lane, LDS dest = wave-uniform base + lane*16
__device__ __forceinline__ void gl2lds16(const void* g, void* l) {
    __builtin_amdgcn_global_load_lds(
        (const __attribute__((address_space(1))) void*)g,
        (__attribute__((address_space(3))) void*)l, 16, 0, 0);
}

// branch-free exact-gelu: erf via Abramowitz-Stegun 7.1.26 (|abs err| <= 1.5e-7)
__device__ __forceinline__ float gelu_fast(float z) {
    const float s = z * 0.70710678118654752f;
    const float ax = fabsf(s);
    const float t = __builtin_amdgcn_rcpf(1.0f + 0.3275911f * ax);
    const float poly = t * (0.254829592f + t * (-0.284496736f +
                       t * (1.421413741f + t * (-1.453152027f + t * 1.061405429f))));
    const float e = __expf(-ax * ax);
    float erfv = 1.0f - poly * e;
    erfv = copysignf(erfv, s);
    return 0.5f * z * (1.0f + erfv);
}

__device__ __forceinline__ float block_sum(float v, float* sbuf) {
    #pragma unroll
    for (int o = 32; o > 0; o >>= 1) v += __shfl_down(v, o, 64);
    const int lane = threadIdx.x & 63, w = threadIdx.x >> 6;
    if (lane == 0) sbuf[w] = v;
    __syncthreads();
    const float r = sbuf[0] + sbuf[1] + sbuf[2] + sbuf[3];
    __syncthreads();
    return r;
}

__global__ __launch_bounds__(256) void avg_kernel(const float* __restrict__ x,
                                                  float* __restrict__ avgx) {
    const int d = blockIdx.x * 256 + threadIdx.x;
    const int b = blockIdx.y;
    const float* xp = x + (size_t)b * NTOK * DIM + d;
    float s = 0.0f;
    for (int n = 0; n < NTOK; ++n) s += xp[(size_t)n * DIM];
    avgx[b * DIM + d] = s * (1.0f / NTOK);
}

// LN -> sigmoid -> A = avg_x*sig, stored fp16; sq computed from fp16-rounded A
__global__ __launch_bounds__(256) void ln_sig_kernel(
    const float* __restrict__ x, const float* __restrict__ gamma,
    const float* __restrict__ beta, const float* __restrict__ avgx,
    __half* __restrict__ Ah, float* __restrict__ sq)
{
    __shared__ float sbuf[4];
    const int row = blockIdx.x;
    const int b = row >> 10;
    const int tid = threadIdx.x;
    const float* xr = x + (size_t)row * DIM;
    float v[3];
    #pragma unroll
    for (int i = 0; i < 3; ++i) v[i] = xr[tid + 256 * i];
    const float mu = block_sum(v[0] + v[1] + v[2], sbuf) * (1.0f / DIM);
    float ss = 0.0f;
    #pragma unroll
    for (int i = 0; i < 3; ++i) { const float d = v[i] - mu; ss += d * d; }
    const float var = block_sum(ss, sbuf) * (1.0f / DIM);
    const float rstd = rsqrtf(var + 1e-5f);
    const float* ag = avgx + b * DIM;
    float qs = 0.0f;
    #pragma unroll
    for (int i = 0; i < 3; ++i) {
        const int d = tid + 256 * i;
        const float ln = (v[i] - mu) * rstd * gamma[d] + beta[d];
        const float sg = 1.0f / (1.0f + expf(-ln));
        const float a = ag[d] * sg;
        const __half h = __float2half(a);
        const float ar = __half2float(h);
        Ah[(size_t)row * DIM + d] = h;
        qs += ar * ar;
    }
    const float tot = block_sum(qs, sbuf);
    if (tid == 0) sq[row] = tot;
}

// fp32 [K][N] -> fp16 [N][K] tiled transpose
__global__ __launch_bounds__(256) void wconv(const float* __restrict__ w,
                                             __half* __restrict__ wT, int K, int N)
{
    __shared__ float t[64][65];
    const int k0 = blockIdx.y * 64, n0 = blockIdx.x * 64;
    const int tid = threadIdx.x;
    const int r = tid >> 4, c4 = (tid & 15) * 4;
    #pragma unroll
    for (int p = 0; p < 4; ++p) {
        const int rr = p * 16 + r;
        const float4 v = *(const float4*)&w[(size_t)(k0 + rr) * N + n0 + c4];
        t[rr][c4] = v.x; t[rr][c4 + 1] = v.y; t[rr][c4 + 2] = v.z; t[rr][c4 + 3] = v.w;
    }
    __syncthreads();
    #pragma unroll
    for (int p = 0; p < 4; ++p) {
        const int nn = p * 16 + r;
        ushort4 pk;
        pk.x = __half_as_ushort(__float2half(t[c4 + 0][nn]));
        pk.y = __half_as_ushort(__float2half(t[c4 + 1][nn]));
        pk.z = __half_as_ushort(__float2half(t[c4 + 2][nn]));
        pk.w = __half_as_ushort(__float2half(t[c4 + 3][nn]));
        *(ushort4*)&wT[(size_t)(n0 + nn) * K + k0 + c4] = pk;
    }
}

__global__ __launch_bounds__(256) void xm_kernel(const float* __restrict__ x,
                                                 const float* __restrict__ m,
                                                 __half* __restrict__ xmH) {
    const int row = blockIdx.x;
    const float mv = m[row];
    #pragma unroll
    for (int i = 0; i < 3; ++i) {
        const int d = threadIdx.x + i * 256;
        xmH[(size_t)row * DIM + d] = __float2half(x[(size_t)row * DIM + d] + mv);
    }
}

// ---- MFMA fp16 GEMM, 128x128 tile, BK=32, 4 waves in 2x2, 4x4 16x16 tiles/wave ----
// A [M][K-contig], BT [N][K-contig]. CAT: A row = [A0 row | A1 row], each DIM wide.
// EPI 0: m1=gelu(z)->fp16 ; 1: h3=m1h*x*gelu(z)->fp16 ; 2: h4=x*gelu(z)->fp16 ; 3: out=gelu(z)->fp32
template<bool CAT, int EPI>
__global__ __launch_bounds__(256) void gemm16(
    const __half* __restrict__ A0, const __half* __restrict__ A1, const int K,
    const __half* __restrict__ BT, const float* __restrict__ bias,
    const float* __restrict__ xin, const __half* __restrict__ m1h,
    __half* __restrict__ outH, float* __restrict__ outF)
{
    __shared__ _Float16 As[128 * 32];
    __shared__ _Float16 Bs[128 * 32];
    const int tid = threadIdx.x;
    const int w = tid >> 6, lane = tid & 63;
    const int wu = __builtin_amdgcn_readfirstlane(w);
    const int wr = w >> 1, wc = w & 1;
    const int R0 = blockIdx.y * 128, J0 = blockIdx.x * 128;
    const int lrow = lane >> 2;            // 0..15 staging row within 16
    const int lk8 = (lane & 3) * 8;        // staging k offset (halves)
    const int rs = CAT ? DIM : K;          // A row stride (halves)

    f32x4 acc[4][4];
    #pragma unroll
    for (int mt = 0; mt < 4; ++mt)
        #pragma unroll
        for (int nt = 0; nt < 4; ++nt) {
            f32x4 z = {0.0f, 0.0f, 0.0f, 0.0f};
            acc[mt][nt] = z;
        }

    for (int k0 = 0; k0 < K; k0 += 32) {
        const __half* Ab = (CAT && k0 >= DIM) ? (A1 + (k0 - DIM)) : (A0 + k0);
        #pragma unroll
        for (int i = 0; i < 2; ++i) {
            const int rbase = i * 64 + w * 16;
            gl2lds16(Ab + (size_t)(R0 + rbase + lrow) * rs + lk8,
                     &As[(size_t)(i * 64 + wu * 16) * 32]);
            gl2lds16(BT + (size_t)(J0 + rbase + lrow) * K + k0 + lk8,
                     &Bs[(size_t)(i * 64 + wu * 16) * 32]);
        }
        __syncthreads();
        f16x8 af[4], bf[4];
        #pragma unroll
        for (int mt = 0; mt < 4; ++mt)
            af[mt] = *(const f16x8*)&As[(wr * 64 + mt * 16 + (lane & 15)) * 32 + (lane >> 4) * 8];
        #pragma unroll
        for (int nt = 0; nt < 4; ++nt)
            bf[nt] = *(const f16x8*)&Bs[(wc * 64 + nt * 16 + (lane & 15)) * 32 + (lane >> 4) * 8];
        #pragma unroll
        for (int mt = 0; mt < 4; ++mt)
            #pragma unroll
            for (int nt = 0; nt < 4; ++nt)
                acc[mt][nt] = __builtin_amdgcn_mfma_f32_16x16x32_f16(af[mt], bf[nt], acc[mt][nt], 0, 0, 0);
        __syncthreads();
    }

    // C/D layout: col = lane&15, row = (lane>>4)*4 + reg
    #pragma unroll
    for (int mt = 0; mt < 4; ++mt) {
        #pragma unroll
        for (int nt = 0; nt < 4; ++nt) {
            const int col = J0 + wc * 64 + nt * 16 + (lane & 15);
            const float bv = bias[col];
            #pragma unroll
            for (int r = 0; r < 4; ++r) {
                const int row = R0 + wr * 64 + mt * 16 + (lane >> 4) * 4 + r;
                const size_t off = (size_t)row * DIM + col;
                const float g = gelu_fast(acc[mt][nt][r] + bv);
                if (EPI == 0) {
                    outH[off] = __float2half(g);
                } else if (EPI == 1) {
                    outH[off] = __float2half(__half2float(m1h[off]) * xin[off] * g);
                } else if (EPI == 2) {
                    outH[off] = __float2half(xin[off] * g);
                } else {
                    outF[off] = g;
                }
            }
        }
    }
}

// dist row-max: per batch full 1024x1024 via 8x8 blocks of 128x128
__global__ __launch_bounds__(256) void dist16(const __half* __restrict__ Ah,
                                              const float* __restrict__ sq,
                                              float* __restrict__ m)
{
    __shared__ _Float16 As[128 * 32];
    __shared__ _Float16 Bs[128 * 32];
    const int tid = threadIdx.x;
    const int w = tid >> 6, lane = tid & 63;
    const int wu = __builtin_amdgcn_readfirstlane(w);
    const int wr = w >> 1, wc = w & 1;
    const int base = blockIdx.z * NTOK;
    const int I0 = blockIdx.y * 128, J0 = blockIdx.x * 128;
    const int lrow = lane >> 2, lk8 = (lane & 3) * 8;

    f32x4 acc[4][4];
    #pragma unroll
    for (int mt = 0; mt < 4; ++mt)
        #pragma unroll
        for (int nt = 0; nt < 4; ++nt) {
            f32x4 z = {0.0f, 0.0f, 0.0f, 0.0f};
            acc[mt][nt] = z;
        }

    for (int k0 = 0; k0 < DIM; k0 += 32) {
        #pragma unroll
        for (int i = 0; i < 2; ++i) {
            const int rbase = i * 64 + w * 16;
            gl2lds16(Ah + (size_t)(base + I0 + rbase + lrow) * DIM + k0 + lk8,
                     &As[(size_t)(i * 64 + wu * 16) * 32]);
            gl2lds16(Ah + (size_t)(base + J0 + rbase + lrow) * DIM + k0 + lk8,
                     &Bs[(size_t)(i * 64 + wu * 16) * 32]);
        }
        __syncthreads();
        f16x8 af[4], bf[4];
        #pragma unroll
        for (int mt = 0; mt < 4; ++mt)
            af[mt] = *(const f16x8*)&As[(wr * 64 + mt * 16 + (lane & 15)) * 32 + (lane >> 4) * 8];
        #pragma unroll
        for (int nt = 0; nt < 4; ++nt)
            bf[nt] = *(const f16x8*)&Bs[(wc * 64 + nt * 16 + (lane & 15)) * 32 + (lane >> 4) * 8];
        #pragma unroll
        for (int mt = 0; mt < 4; ++mt)
            #pragma unroll
            for (int nt = 0; nt < 4; ++nt)
                acc[mt][nt] = __builtin_amdgcn_mfma_f32_16x16x32_f16(af[mt], bf[nt], acc[mt][nt], 0, 0, 0);
        __syncthreads();
    }

    #pragma unroll
    for (int mt = 0; mt < 4; ++mt) {
        float sqi[4];
        #pragma unroll
        for (int r = 0; r < 4; ++r)
            sqi[r] = sq[base + I0 + wr * 64 + mt * 16 + (lane >> 4) * 4 + r];
        float vmax[4] = {0.0f, 0.0f, 0.0f, 0.0f};
        #pragma unroll
        for (int nt = 0; nt < 4; ++nt) {
            const float sqj = sq[base + J0 + wc * 64 + nt * 16 + (lane & 15)];
            #pragma unroll
            for (int r = 0; r < 4; ++r) {
                const float d2 = sqi[r] + sqj - 2.0f * acc[mt][nt][r];
                vmax[r] = fmaxf(vmax[r], sqrtf(fmaxf(d2, 1e-12f)));
            }
        }
        #pragma unroll
        for (int r = 0; r < 4; ++r) {
            float v = vmax[r];
            v = fmaxf(v, __shfl_xor(v, 1, 64));
            v = fmaxf(v, __shfl_xor(v, 2, 64));
            v = fmaxf(v, __shfl_xor(v, 4, 64));
            v = fmaxf(v, __shfl_xor(v, 8, 64));
            if ((lane & 15) == 0)
                atomicMax((unsigned int*)&m[base + I0 + wr * 64 + mt * 16 + (lane >> 4) * 4 + r],
                          __float_as_uint(v));
        }
    }
}

extern "C" void kernel_launch(void* const* d_in, const int* in_sizes, int n_in,
                              void* d_out, int out_size, void* d_ws, size_t ws_size,
                              hipStream_t stream)
{
    const float* x     = (const float*)d_in[0];
    const float* gamma = (const float*)d_in[1];
    const float* beta  = (const float*)d_in[2];
    const float* w1    = (const float*)d_in[3];
    const float* b1    = (const float*)d_in[4];
    const float* w2    = (const float*)d_in[5];
    const float* b2    = (const float*)d_in[6];
    const float* w3    = (const float*)d_in[7];
    const float* b3    = (const float*)d_in[8];
    const float* w4    = (const float*)d_in[9];
    const float* b4    = (const float*)d_in[10];
    float* out = (float*)d_out;
    float* ws  = (float*)d_ws;

    // ws: avgx[12288] sq[16384] m[16384] | w1T..w4T fp16 | P0,P1 fp16 [BNR*DIM]
    float* avgx = ws;
    float* sq   = ws + 12288;
    float* mbuf = sq + 16384;
    __half* w1T = (__half*)(mbuf + 16384);
    __half* w2T = w1T + (size_t)1536 * 768;
    __half* w3T = w2T + (size_t)768 * 768;
    __half* w4T = w3T + (size_t)768 * 768;
    __half* P0  = w4T + (size_t)768 * 768;            // m1H, later h4H
    __half* P1  = P0 + (size_t)BNR * DIM;             // h3H
    // d_out hosts the two L1-only fp16 operands (dead before L4 writes out)
    __half* Ah  = (__half*)d_out;
    __half* xmH = Ah + (size_t)BNR * DIM;

    hipMemsetAsync(mbuf, 0, BNR * sizeof(float), stream);
    wconv<<<dim3(12, 24), 256, 0, stream>>>(w1, w1T, 1536, 768);
    wconv<<<dim3(12, 12), 256, 0, stream>>>(w2, w2T, 768, 768);
    wconv<<<dim3(12, 12), 256, 0, stream>>>(w3, w3T, 768, 768);
    wconv<<<dim3(12, 12), 256, 0, stream>>>(w4, w4T, 768, 768);
    avg_kernel<<<dim3(3, NBATCH), 256, 0, stream>>>(x, avgx);
    ln_sig_kernel<<<BNR, 256, 0, stream>>>(x, gamma, beta, avgx, Ah, sq);
    dist16<<<dim3(8, 8, NBATCH), 256, 0, stream>>>(Ah, sq, mbuf);
    xm_kernel<<<BNR, 256, 0, stream>>>(x, mbuf, xmH);
    // L1: m1 = gelu(cat @ w1 + b1)
    gemm16<true, 0><<<dim3(6, 128), 256, 0, stream>>>(
        Ah, xmH, 2 * DIM, w1T, b1, nullptr, nullptr, P0, nullptr);
    // L2: h3 = m1 * x * gelu(m1 @ w2 + b2)
    gemm16<false, 1><<<dim3(6, 128), 256, 0, stream>>>(
        P0, nullptr, DIM, w2T, b2, x, P0, P1, nullptr);
    // L3: h4 = x * gelu(h3 @ w3 + b3)
    gemm16<false, 2><<<dim3(6, 128), 256, 0, stream>>>(
        P1, nullptr, DIM, w3T, b3, x, nullptr, P0, nullptr);
    // L4: out = gelu(h4 @ w4 + b4)
    gemm16<false, 3><<<dim3(6, 128), 256, 0, stream>>>(
        P0, nullptr, DIM, w4T, b4, x, nullptr, nullptr, out);
}